// Round 1
// baseline (174.375 us; speedup 1.0000x reference)
//
#include <hip/hip_runtime.h>
#include <math.h>

// Problem constants (match reference)
#define KOBJ  512
#define NCLS  6
#define QMIN  0.1f
#define EPSF  1e-9f

// Workspace overlay (zeroed via hipMemsetAsync each launch)
struct Ws {
    unsigned long long packed[KOBJ];   // argmax key: (beta_bits<<32) | ~hit_idx
    int   count[KOBJ];                 // hits per object
    float num[KOBJ];                   // sum payload*pw
    float den[KOBJ];                   // sum pw
    float xk0[KOBJ];                   // x_alpha coords
    float xk1[KOBJ];
    float qw_rep[KOBJ];                // flag * q_a / (N - cnt + eps) / n_obj
    float qw_att[KOBJ];                // flag * q_a / (cnt + eps) / n_obj
    float scal[8];                     // 0:att 1:rep 2:noiseBetaSum 3:noiseCnt 4:ccSqSum 5:(L_beta+L_pay)
};

__device__ __forceinline__ float clipb(float b) {
    return fminf(fmaxf(b, 1e-6f), 1.0f - 1e-6f);
}

__device__ __forceinline__ float waveSum(float v) {
#pragma unroll
    for (int o = 32; o > 0; o >>= 1) v += __shfl_down(v, o, 64);
    return v;
}

// ---------------- Kernel 1: per-hit scatter reductions ----------------
__global__ __launch_bounds__(256)
void k_hits(const float* __restrict__ beta_in, const float* __restrict__ cc,
            const float* __restrict__ pe,  const float* __restrict__ ppos,
            const float* __restrict__ pt,  const float* __restrict__ pid,
            const int*   __restrict__ tidx,const float* __restrict__ te,
            const float* __restrict__ tpos,const float* __restrict__ tt,
            Ws* ws, int n)
{
    int i = blockIdx.x * blockDim.x + threadIdx.x;
    float ccs = 0.f, nb = 0.f, nc = 0.f;
    if (i < n) {
        float b  = clipb(beta_in[i]);
        float c0 = cc[2*i], c1 = cc[2*i+1];
        ccs = c0*c0 + c1*c1;
        int k = tidx[i];
        if (k >= 0) {
            // argmax-beta with first-index tie-break (larger ~i == smaller i)
            unsigned long long key =
                ((unsigned long long)__float_as_uint(b) << 32) | (unsigned)(~i);
            atomicMax(&ws->packed[k], key);
            atomicAdd(&ws->count[k], 1);

            // payload losses
            float tei   = te[i];
            float ediff = fabsf(tei - pe[i]);
            float el = 10.f * expf(-0.1f * ediff * ediff) + 0.01f * ediff;
            { float x = el * 0.1f; if (x > 1.f) x = logf(x + 1.f); el = x * 10.f; }

            float dx  = tpos[2*i]   - ppos[2*i];
            float dy  = tpos[2*i+1] - ppos[2*i+1];
            float d2p = dx*dx + dy*dy;
            float hx  = sqrtf(d2p * 0.01f + 0.01f);          // >= 0
            float pl  = (hx < 10.f) ? hx*hx : 100.f + 20.f*(hx - 10.f);
            { float x = pl * (1.f/3.f); if (x > 1.f) x = logf(x + 1.f); pl = x * 3.f; }

            float td  = tt[i] - pt[i];
            float atd = fabsf(td);
            float tl  = (atd < 2.f) ? td*td : 4.f + 4.f*(atd - 2.f);
            { float x = tl * (1.f/6.f); if (x > 1.f) x = logf(x + 1.f); tl = x * 6.f; }

            float cls = 0.f;
#pragma unroll
            for (int j = 0; j < NCLS; ++j) { float v = pid[i*NCLS + j]; cls += v*v; }
            cls *= (1e-8f / (float)NCLS);

            float payload = el + pl + tl + cls;
            float ew = (tei > 10.f) ? 1.f : (tei - 0.5f) * (1.f / 9.5f);
            ew = fmaxf(ew, 0.f);
            float pw = b * ew;
            atomicAdd(&ws->num[k], payload * pw);
            atomicAdd(&ws->den[k], pw);
        } else {
            nb = b; nc = 1.f;
        }
    }
    // block-reduce ccs/nb/nc, one atomic each per block
    __shared__ float s0[4], s1[4], s2[4];
    float a = waveSum(ccs), bb = waveSum(nb), cN = waveSum(nc);
    int lane = threadIdx.x & 63, w = threadIdx.x >> 6;
    if (lane == 0) { s0[w] = a; s1[w] = bb; s2[w] = cN; }
    __syncthreads();
    if (threadIdx.x == 0) {
        float A = 0.f, B = 0.f, Cc = 0.f;
        for (int j = 0; j < 4; ++j) { A += s0[j]; B += s1[j]; Cc += s2[j]; }
        atomicAdd(&ws->scal[4], A);
        atomicAdd(&ws->scal[2], B);
        atomicAdd(&ws->scal[3], Cc);
    }
}

// ---------------- Kernel 2: per-object setup (1 block, 512 threads) ----------------
__global__ __launch_bounds__(KOBJ)
void k_obj(const float* __restrict__ beta_in, const float* __restrict__ cc,
           Ws* ws, int n)
{
    int k = threadIdx.x;
    int cnt = ws->count[k];
    float flag = (cnt > 0) ? 1.f : 0.f;
    float beta_a = 0.f, q_a = 0.f, x0 = 0.f, x1 = 0.f, payk = 0.f;
    if (cnt > 0) {
        unsigned idx = ~(unsigned)(ws->packed[k] & 0xffffffffull);
        float b = clipb(beta_in[idx]);
        beta_a = b;
        float at = 0.5f * logf((1.f + b) / (1.f - b));   // arctanh
        q_a = at * at + QMIN;
        x0 = cc[2*idx]; x1 = cc[2*idx + 1];
        payk = ws->num[k] / (ws->den[k] + EPSF);
    }
    // reduce: n_obj count, sum(1-beta_a), sum(payk)
    __shared__ float r0[8], r1[8], r2[8];
    __shared__ float s_inv_nobj;
    float f = waveSum(flag);
    float bsum = waveSum(flag * (1.f - beta_a));
    float psum = waveSum(payk);
    int lane = threadIdx.x & 63, w = threadIdx.x >> 6;
    if (lane == 0) { r0[w] = f; r1[w] = bsum; r2[w] = psum; }
    __syncthreads();
    if (threadIdx.x == 0) {
        float F = 0.f, Bs = 0.f, Ps = 0.f;
        for (int j = 0; j < 8; ++j) { F += r0[j]; Bs += r1[j]; Ps += r2[j]; }
        float n_obj = F + EPSF;
        s_inv_nobj = 1.f / n_obj;
        ws->scal[5] = (Bs + Ps) / n_obj;   // L_beta + L_pay
    }
    __syncthreads();
    float inv_nobj = s_inv_nobj;
    ws->xk0[k] = x0;
    ws->xk1[k] = x1;
    ws->qw_rep[k] = flag * q_a * (1.f / ((float)n - (float)cnt + EPSF)) * inv_nobj;
    ws->qw_att[k] = flag * q_a * (1.f / ((float)cnt + EPSF)) * inv_nobj;
}

// ---------------- Kernel 3: N x K pairwise attraction/repulsion ----------------
__global__ __launch_bounds__(256)
void k_pair(const float* __restrict__ beta_in, const float* __restrict__ cc,
            const int* __restrict__ tidx, Ws* ws, int n)
{
    __shared__ float sx0[KOBJ], sx1[KOBJ], sqw[KOBJ];
    for (int k = threadIdx.x; k < KOBJ; k += blockDim.x) {
        sx0[k] = ws->xk0[k]; sx1[k] = ws->xk1[k]; sqw[k] = ws->qw_rep[k];
    }
    __syncthreads();

    int i = blockIdx.x * blockDim.x + threadIdx.x;
    float att = 0.f, rep = 0.f;
    if (i < n) {
        float c0 = cc[2*i], c1 = cc[2*i+1];
        float b  = clipb(beta_in[i]);
        float at = 0.5f * logf((1.f + b) / (1.f - b));
        float q  = at * at + QMIN;

        float acc = 0.f;
#pragma unroll 8
        for (int k = 0; k < KOBJ; ++k) {
            float dx = c0 - sx0[k], dy = c1 - sx1[k];
            float d2 = dx*dx + dy*dy;
            float r  = sqrtf(d2 + 1e-6f);
            acc = fmaf(fmaxf(1.f - r, 0.f), sqw[k], acc);
        }
        int k0 = tidx[i];
        if (k0 >= 0) {
            // remove self-repulsion with the EXACT same fp ops -> exact cancel
            float dx = c0 - sx0[k0], dy = c1 - sx1[k0];
            float d2 = dx*dx + dy*dy;
            float r  = sqrtf(d2 + 1e-6f);
            acc -= fmaxf(1.f - r, 0.f) * sqw[k0];
            att  = d2 * ws->qw_att[k0] * q;
        }
        rep = acc * q;
    }
    __shared__ float s0[4], s1[4];
    float A = waveSum(att), R = waveSum(rep);
    int lane = threadIdx.x & 63, w = threadIdx.x >> 6;
    if (lane == 0) { s0[w] = A; s1[w] = R; }
    __syncthreads();
    if (threadIdx.x == 0) {
        float sa = 0.f, sr = 0.f;
        for (int j = 0; j < 4; ++j) { sa += s0[j]; sr += s1[j]; }
        atomicAdd(&ws->scal[0], sa);
        atomicAdd(&ws->scal[1], sr);
    }
}

// ---------------- Kernel 4: final combine ----------------
__global__ void k_final(Ws* ws, float* out, int n)
{
    float L_noise = ws->scal[2] / (ws->scal[3] + EPSF);
    float L_cc    = 0.001f * ws->scal[4] / (float)(n * 2);
    out[0] = ws->scal[0] + ws->scal[1] + ws->scal[5] + L_noise + L_cc;
}

extern "C" void kernel_launch(void* const* d_in, const int* in_sizes, int n_in,
                              void* d_out, int out_size, void* d_ws, size_t ws_size,
                              hipStream_t stream)
{
    const float* pred_beta    = (const float*)d_in[0];
    const float* pred_ccoords = (const float*)d_in[1];
    const float* pred_energy  = (const float*)d_in[2];
    const float* pred_pos     = (const float*)d_in[3];
    const float* pred_time    = (const float*)d_in[4];
    const float* pred_id      = (const float*)d_in[5];
    const int*   t_idx        = (const int*)d_in[6];
    const float* t_energy     = (const float*)d_in[7];
    const float* t_pos        = (const float*)d_in[8];
    const float* t_time       = (const float*)d_in[9];
    // t_pid (d_in[10]) unused by the reference's classification loss

    float* out = (float*)d_out;
    Ws* ws = (Ws*)d_ws;
    const int n = in_sizes[0];   // 80000

    // workspace is re-poisoned to 0xAA before every replay -> zero it here
    hipMemsetAsync(ws, 0, sizeof(Ws), stream);

    const int B = 256;
    const int G = (n + B - 1) / B;
    k_hits<<<G, B, 0, stream>>>(pred_beta, pred_ccoords, pred_energy, pred_pos,
                                pred_time, pred_id, t_idx, t_energy, t_pos,
                                t_time, ws, n);
    k_obj<<<1, KOBJ, 0, stream>>>(pred_beta, pred_ccoords, ws, n);
    k_pair<<<G, B, 0, stream>>>(pred_beta, pred_ccoords, t_idx, ws, n);
    k_final<<<1, 1, 0, stream>>>(ws, out, n);
}

// Round 2
// 156.360 us; speedup vs baseline: 1.1152x; 1.1152x over previous
//
#include <hip/hip_runtime.h>
#include <math.h>

// Problem constants (match reference)
#define KOBJ  512
#define NCLS  6
#define QMIN  0.1f
#define EPSF  1e-9f

// k_pair tiling
#define KC 64      // K-chunk per y-block (512/64 = 8 y-blocks)
#define HP 4       // hits per thread

// Workspace overlay (zeroed via hipMemsetAsync each launch).
// kvec first for 16B alignment.
struct Ws {
    float kvec[KOBJ * 4];              // per-object {x0, x1, qw_rep, qw_att}
    unsigned long long packed[KOBJ];   // argmax key: (beta_bits<<32) | ~hit_idx
    int   count[KOBJ];                 // hits per object
    float num[KOBJ];                   // sum payload*pw
    float den[KOBJ];                   // sum pw
    float scal[8];                     // 0:att 1:rep 2:noiseBetaSum 3:noiseCnt 4:ccSqSum 5:(L_beta+L_pay)
};

__device__ __forceinline__ float clipb(float b) {
    return fminf(fmaxf(b, 1e-6f), 1.0f - 1e-6f);
}

__device__ __forceinline__ float waveSum(float v) {
#pragma unroll
    for (int o = 32; o > 0; o >>= 1) v += __shfl_down(v, o, 64);
    return v;
}

// ---------------- Kernel 1: per-hit scatter reductions ----------------
__global__ __launch_bounds__(256)
void k_hits(const float* __restrict__ beta_in, const float* __restrict__ cc,
            const float* __restrict__ pe,  const float* __restrict__ ppos,
            const float* __restrict__ pt,  const float* __restrict__ pid,
            const int*   __restrict__ tidx,const float* __restrict__ te,
            const float* __restrict__ tpos,const float* __restrict__ tt,
            Ws* ws, int n)
{
    int i = blockIdx.x * blockDim.x + threadIdx.x;
    float ccs = 0.f, nb = 0.f, nc = 0.f;
    if (i < n) {
        float b  = clipb(beta_in[i]);
        float c0 = cc[2*i], c1 = cc[2*i+1];
        ccs = c0*c0 + c1*c1;
        int k = tidx[i];
        if (k >= 0) {
            // argmax-beta with first-index tie-break (larger ~i == smaller i)
            unsigned long long key =
                ((unsigned long long)__float_as_uint(b) << 32) | (unsigned)(~i);
            atomicMax(&ws->packed[k], key);
            atomicAdd(&ws->count[k], 1);

            // payload losses
            float tei   = te[i];
            float ediff = fabsf(tei - pe[i]);
            float el = 10.f * expf(-0.1f * ediff * ediff) + 0.01f * ediff;
            { float x = el * 0.1f; if (x > 1.f) x = logf(x + 1.f); el = x * 10.f; }

            float dx  = tpos[2*i]   - ppos[2*i];
            float dy  = tpos[2*i+1] - ppos[2*i+1];
            float d2p = dx*dx + dy*dy;
            float hx  = sqrtf(d2p * 0.01f + 0.01f);          // >= 0
            float pl  = (hx < 10.f) ? hx*hx : 100.f + 20.f*(hx - 10.f);
            { float x = pl * (1.f/3.f); if (x > 1.f) x = logf(x + 1.f); pl = x * 3.f; }

            float td  = tt[i] - pt[i];
            float atd = fabsf(td);
            float tl  = (atd < 2.f) ? td*td : 4.f + 4.f*(atd - 2.f);
            { float x = tl * (1.f/6.f); if (x > 1.f) x = logf(x + 1.f); tl = x * 6.f; }

            float cls = 0.f;
#pragma unroll
            for (int j = 0; j < NCLS; ++j) { float v = pid[i*NCLS + j]; cls += v*v; }
            cls *= (1e-8f / (float)NCLS);

            float payload = el + pl + tl + cls;
            float ew = (tei > 10.f) ? 1.f : (tei - 0.5f) * (1.f / 9.5f);
            ew = fmaxf(ew, 0.f);
            float pw = b * ew;
            atomicAdd(&ws->num[k], payload * pw);
            atomicAdd(&ws->den[k], pw);
        } else {
            nb = b; nc = 1.f;
        }
    }
    // block-reduce ccs/nb/nc, one atomic each per block
    __shared__ float s0[4], s1[4], s2[4];
    float a = waveSum(ccs), bb = waveSum(nb), cN = waveSum(nc);
    int lane = threadIdx.x & 63, w = threadIdx.x >> 6;
    if (lane == 0) { s0[w] = a; s1[w] = bb; s2[w] = cN; }
    __syncthreads();
    if (threadIdx.x == 0) {
        float A = 0.f, B = 0.f, Cc = 0.f;
        for (int j = 0; j < 4; ++j) { A += s0[j]; B += s1[j]; Cc += s2[j]; }
        atomicAdd(&ws->scal[4], A);
        atomicAdd(&ws->scal[2], B);
        atomicAdd(&ws->scal[3], Cc);
    }
}

// ---------------- Kernel 2: per-object setup (1 block, 512 threads) ----------------
__global__ __launch_bounds__(KOBJ)
void k_obj(const float* __restrict__ beta_in, const float* __restrict__ cc,
           Ws* ws, int n)
{
    int k = threadIdx.x;
    int cnt = ws->count[k];
    float flag = (cnt > 0) ? 1.f : 0.f;
    float beta_a = 0.f, q_a = 0.f, x0 = 0.f, x1 = 0.f, payk = 0.f;
    if (cnt > 0) {
        unsigned idx = ~(unsigned)(ws->packed[k] & 0xffffffffull);
        float b = clipb(beta_in[idx]);
        beta_a = b;
        float at = 0.5f * logf((1.f + b) / (1.f - b));   // arctanh
        q_a = at * at + QMIN;
        x0 = cc[2*idx]; x1 = cc[2*idx + 1];
        payk = ws->num[k] / (ws->den[k] + EPSF);
    }
    // reduce: n_obj count, sum(1-beta_a), sum(payk)
    __shared__ float r0[8], r1[8], r2[8];
    __shared__ float s_inv_nobj;
    float f = waveSum(flag);
    float bsum = waveSum(flag * (1.f - beta_a));
    float psum = waveSum(payk);
    int lane = threadIdx.x & 63, w = threadIdx.x >> 6;
    if (lane == 0) { r0[w] = f; r1[w] = bsum; r2[w] = psum; }
    __syncthreads();
    if (threadIdx.x == 0) {
        float F = 0.f, Bs = 0.f, Ps = 0.f;
        for (int j = 0; j < 8; ++j) { F += r0[j]; Bs += r1[j]; Ps += r2[j]; }
        float n_obj = F + EPSF;
        s_inv_nobj = 1.f / n_obj;
        ws->scal[5] = (Bs + Ps) / n_obj;   // L_beta + L_pay
    }
    __syncthreads();
    float inv_nobj = s_inv_nobj;
    ws->kvec[4*k + 0] = x0;
    ws->kvec[4*k + 1] = x1;
    ws->kvec[4*k + 2] = flag * q_a * (1.f / ((float)n - (float)cnt + EPSF)) * inv_nobj;  // qw_rep
    ws->kvec[4*k + 3] = flag * q_a * (1.f / ((float)cnt + EPSF)) * inv_nobj;             // qw_att
}

// ---------------- Kernel 3: N x K pairwise attraction/repulsion ----------------
// grid: (ceil(n / (256*HP)), KOBJ/KC). Each thread: HP hits x KC objects.
__global__ __launch_bounds__(256)
void k_pair(const float* __restrict__ beta_in, const float* __restrict__ cc,
            const int* __restrict__ tidx, Ws* ws, int n, int xspan)
{
    __shared__ float4 sk[KC];
    int kbase = blockIdx.y * KC;
    if (threadIdx.x < KC)
        sk[threadIdx.x] = ((const float4*)ws->kvec)[kbase + threadIdx.x];
    __syncthreads();

    int i0 = blockIdx.x * 256 + threadIdx.x;

    float c0[HP], c1[HP], q[HP], acc[HP];
    int   k0[HP];
#pragma unroll
    for (int j = 0; j < HP; ++j) {
        int i = i0 + j * xspan;
        bool v = (i < n);
        // invalid lanes: park far away -> relu(1 - r) == 0, k0 = -1 guards att
        c0[j] = v ? cc[2*i]     : 1e30f;
        c1[j] = v ? cc[2*i + 1] : 1e30f;
        float b = v ? clipb(beta_in[i]) : 0.5f;
        float at = 0.5f * logf((1.f + b) / (1.f - b));
        q[j] = at * at + QMIN;
        k0[j] = v ? tidx[i] : -1;
        acc[j] = 0.f;
    }

#pragma unroll 4
    for (int k = 0; k < KC; ++k) {
        float4 kv = sk[k];
#pragma unroll
        for (int j = 0; j < HP; ++j) {
            float dx = c0[j] - kv.x, dy = c1[j] - kv.y;
            float d2 = dx*dx + dy*dy;
            float r  = sqrtf(d2 + 1e-6f);
            acc[j] = fmaf(fmaxf(1.f - r, 0.f), kv.z, acc[j]);
        }
    }

    float att = 0.f, rep = 0.f;
#pragma unroll
    for (int j = 0; j < HP; ++j) {
        int kk = k0[j] - kbase;
        if (kk >= 0 && kk < KC) {
            // remove self-repulsion with the same fp formula (error ~ulp, << tol)
            float4 kv = sk[kk];
            float dx = c0[j] - kv.x, dy = c1[j] - kv.y;
            float d2 = dx*dx + dy*dy;
            float r  = sqrtf(d2 + 1e-6f);
            acc[j] -= fmaxf(1.f - r, 0.f) * kv.z;
            att = fmaf(d2 * kv.w, q[j], att);
        }
        rep = fmaf(acc[j], q[j], rep);
    }

    __shared__ float s0[4], s1[4];
    float A = waveSum(att), R = waveSum(rep);
    int lane = threadIdx.x & 63, w = threadIdx.x >> 6;
    if (lane == 0) { s0[w] = A; s1[w] = R; }
    __syncthreads();
    if (threadIdx.x == 0) {
        float sa = 0.f, sr = 0.f;
        for (int j = 0; j < 4; ++j) { sa += s0[j]; sr += s1[j]; }
        atomicAdd(&ws->scal[0], sa);
        atomicAdd(&ws->scal[1], sr);
    }
}

// ---------------- Kernel 4: final combine ----------------
__global__ void k_final(Ws* ws, float* out, int n)
{
    float L_noise = ws->scal[2] / (ws->scal[3] + EPSF);
    float L_cc    = 0.001f * ws->scal[4] / (float)(n * 2);
    out[0] = ws->scal[0] + ws->scal[1] + ws->scal[5] + L_noise + L_cc;
}

extern "C" void kernel_launch(void* const* d_in, const int* in_sizes, int n_in,
                              void* d_out, int out_size, void* d_ws, size_t ws_size,
                              hipStream_t stream)
{
    const float* pred_beta    = (const float*)d_in[0];
    const float* pred_ccoords = (const float*)d_in[1];
    const float* pred_energy  = (const float*)d_in[2];
    const float* pred_pos     = (const float*)d_in[3];
    const float* pred_time    = (const float*)d_in[4];
    const float* pred_id      = (const float*)d_in[5];
    const int*   t_idx        = (const int*)d_in[6];
    const float* t_energy     = (const float*)d_in[7];
    const float* t_pos        = (const float*)d_in[8];
    const float* t_time       = (const float*)d_in[9];
    // t_pid (d_in[10]) unused by the reference's classification loss

    float* out = (float*)d_out;
    Ws* ws = (Ws*)d_ws;
    const int n = in_sizes[0];   // 80000

    // workspace is re-poisoned to 0xAA before every replay -> zero it here
    hipMemsetAsync(ws, 0, sizeof(Ws), stream);

    const int B = 256;
    const int G = (n + B - 1) / B;
    k_hits<<<G, B, 0, stream>>>(pred_beta, pred_ccoords, pred_energy, pred_pos,
                                pred_time, pred_id, t_idx, t_energy, t_pos,
                                t_time, ws, n);
    k_obj<<<1, KOBJ, 0, stream>>>(pred_beta, pred_ccoords, ws, n);

    const int GX = (n + B * HP - 1) / (B * HP);      // 79 for n=80000
    dim3 gp(GX, KOBJ / KC);                          // 79 x 8 = 632 blocks
    k_pair<<<gp, B, 0, stream>>>(pred_beta, pred_ccoords, t_idx, ws, n, GX * B);

    k_final<<<1, 1, 0, stream>>>(ws, out, n);
}

// Round 3
// 138.680 us; speedup vs baseline: 1.2574x; 1.1275x over previous
//
#include <hip/hip_runtime.h>
#include <math.h>

// Problem constants (match reference)
#define KOBJ  512
#define NCLS  6
#define QMIN  0.1f
#define EPSF  1e-9f

// k_pair tiling
#define KC 64      // K-chunk per y-block (512/64 = 8 y-blocks)
#define HP 4       // hits per thread

// k_hits two-stage reduction
#define NB 32      // stage-A blocks (partials per object)

// Workspace overlay. Only scal[] needs zeroing (partials are fully
// overwritten by every stage-A block; kvec fully written by k_obj).
struct Ws {
    float kvec[KOBJ * 4];                     // per-object {x0, x1, qw_rep, qw_att} (16B aligned)
    unsigned long long p_packed[KOBJ][NB];    // per-block argmax keys
    float p_num[KOBJ][NB];                    // per-block sum payload*pw
    float p_den[KOBJ][NB];                    // per-block sum pw
    int   p_cnt[KOBJ][NB];                    // per-block hit counts
    float scal[8];                            // 0:att 1:rep 2:noiseBetaSum 3:noiseCnt 4:ccSqSum 5:(L_beta+L_pay)
};

__device__ __forceinline__ float clipb(float b) {
    return fminf(fmaxf(b, 1e-6f), 1.0f - 1e-6f);
}

__device__ __forceinline__ float waveSum(float v) {
#pragma unroll
    for (int o = 32; o > 0; o >>= 1) v += __shfl_down(v, o, 64);
    return v;
}

// ---------------- Kernel 1 (stage A): per-hit -> per-block LDS -> partial stores ----
__global__ __launch_bounds__(1024)
void k_hits(const float* __restrict__ beta_in, const float* __restrict__ cc,
            const float* __restrict__ pe,  const float* __restrict__ ppos,
            const float* __restrict__ pt,  const float* __restrict__ pid,
            const int*   __restrict__ tidx,const float* __restrict__ te,
            const float* __restrict__ tpos,const float* __restrict__ tt,
            Ws* ws, int n)
{
    __shared__ unsigned long long lpk[KOBJ];
    __shared__ float lnum[KOBJ], lden[KOBJ];
    __shared__ int   lcnt[KOBJ];
    for (int k = threadIdx.x; k < KOBJ; k += 1024) {
        lpk[k] = 0ull; lnum[k] = 0.f; lden[k] = 0.f; lcnt[k] = 0;
    }
    __syncthreads();

    float ccs = 0.f, nb = 0.f, nc = 0.f;
    for (int i = blockIdx.x * 1024 + threadIdx.x; i < n; i += NB * 1024) {
        float b  = clipb(beta_in[i]);
        float c0 = cc[2*i], c1 = cc[2*i+1];
        ccs += c0*c0 + c1*c1;
        int k = tidx[i];
        if (k >= 0) {
            // argmax-beta, first-index tie-break (larger ~i == smaller i)
            unsigned long long key =
                ((unsigned long long)__float_as_uint(b) << 32) | (unsigned)(~i);
            atomicMax(&lpk[k], key);
            atomicAdd(&lcnt[k], 1);

            // payload losses
            float tei   = te[i];
            float ediff = fabsf(tei - pe[i]);
            float el = 10.f * expf(-0.1f * ediff * ediff) + 0.01f * ediff;
            { float x = el * 0.1f; if (x > 1.f) x = logf(x + 1.f); el = x * 10.f; }

            float dx  = tpos[2*i]   - ppos[2*i];
            float dy  = tpos[2*i+1] - ppos[2*i+1];
            float d2p = dx*dx + dy*dy;
            float hx  = sqrtf(d2p * 0.01f + 0.01f);          // >= 0
            float pl  = (hx < 10.f) ? hx*hx : 100.f + 20.f*(hx - 10.f);
            { float x = pl * (1.f/3.f); if (x > 1.f) x = logf(x + 1.f); pl = x * 3.f; }

            float td  = tt[i] - pt[i];
            float atd = fabsf(td);
            float tl  = (atd < 2.f) ? td*td : 4.f + 4.f*(atd - 2.f);
            { float x = tl * (1.f/6.f); if (x > 1.f) x = logf(x + 1.f); tl = x * 6.f; }

            float cls = 0.f;
#pragma unroll
            for (int j = 0; j < NCLS; ++j) { float v = pid[i*NCLS + j]; cls += v*v; }
            cls *= (1e-8f / (float)NCLS);

            float payload = el + pl + tl + cls;
            float ew = (tei > 10.f) ? 1.f : (tei - 0.5f) * (1.f / 9.5f);
            ew = fmaxf(ew, 0.f);
            float pw = b * ew;
            atomicAdd(&lnum[k], payload * pw);
            atomicAdd(&lden[k], pw);
        } else {
            nb += b; nc += 1.f;
        }
    }
    __syncthreads();

    // flush per-block partials with plain stores (no global atomics)
    for (int k = threadIdx.x; k < KOBJ; k += 1024) {
        ws->p_packed[k][blockIdx.x] = lpk[k];
        ws->p_num[k][blockIdx.x]    = lnum[k];
        ws->p_den[k][blockIdx.x]    = lden[k];
        ws->p_cnt[k][blockIdx.x]    = lcnt[k];
    }

    // block-reduce ccs/nb/nc -> one atomic each per block (32 blocks total)
    __shared__ float s0[16], s1[16], s2[16];
    float a = waveSum(ccs), bb = waveSum(nb), cN = waveSum(nc);
    int lane = threadIdx.x & 63, w = threadIdx.x >> 6;
    if (lane == 0) { s0[w] = a; s1[w] = bb; s2[w] = cN; }
    __syncthreads();
    if (threadIdx.x == 0) {
        float A = 0.f, B = 0.f, Cc = 0.f;
        for (int j = 0; j < 16; ++j) { A += s0[j]; B += s1[j]; Cc += s2[j]; }
        atomicAdd(&ws->scal[4], A);
        atomicAdd(&ws->scal[2], B);
        atomicAdd(&ws->scal[3], Cc);
    }
}

// ---------------- Kernel 2 (stage B): reduce partials + per-object setup ----------
__global__ __launch_bounds__(KOBJ)
void k_obj(const float* __restrict__ beta_in, const float* __restrict__ cc,
           Ws* ws, int n)
{
    int k = threadIdx.x;

    unsigned long long pk = 0ull;
    float numk = 0.f, denk = 0.f;
    int   cnt  = 0;
#pragma unroll 8
    for (int b = 0; b < NB; ++b) {
        unsigned long long v = ws->p_packed[k][b];
        pk = (v > pk) ? v : pk;
        numk += ws->p_num[k][b];
        denk += ws->p_den[k][b];
        cnt  += ws->p_cnt[k][b];
    }

    float flag = (cnt > 0) ? 1.f : 0.f;
    float beta_a = 0.f, q_a = 0.f, x0 = 0.f, x1 = 0.f, payk = 0.f;
    if (cnt > 0) {
        unsigned idx = ~(unsigned)(pk & 0xffffffffull);
        float b = clipb(beta_in[idx]);
        beta_a = b;
        float at = 0.5f * logf((1.f + b) / (1.f - b));   // arctanh
        q_a = at * at + QMIN;
        x0 = cc[2*idx]; x1 = cc[2*idx + 1];
        payk = numk / (denk + EPSF);
    }
    // reduce: n_obj count, sum(1-beta_a), sum(payk)
    __shared__ float r0[8], r1[8], r2[8];
    __shared__ float s_inv_nobj;
    float f = waveSum(flag);
    float bsum = waveSum(flag * (1.f - beta_a));
    float psum = waveSum(payk);
    int lane = threadIdx.x & 63, w = threadIdx.x >> 6;
    if (lane == 0) { r0[w] = f; r1[w] = bsum; r2[w] = psum; }
    __syncthreads();
    if (threadIdx.x == 0) {
        float F = 0.f, Bs = 0.f, Ps = 0.f;
        for (int j = 0; j < 8; ++j) { F += r0[j]; Bs += r1[j]; Ps += r2[j]; }
        float n_obj = F + EPSF;
        s_inv_nobj = 1.f / n_obj;
        ws->scal[5] = (Bs + Ps) / n_obj;   // L_beta + L_pay
    }
    __syncthreads();
    float inv_nobj = s_inv_nobj;
    ws->kvec[4*k + 0] = x0;
    ws->kvec[4*k + 1] = x1;
    ws->kvec[4*k + 2] = flag * q_a * (1.f / ((float)n - (float)cnt + EPSF)) * inv_nobj;  // qw_rep
    ws->kvec[4*k + 3] = flag * q_a * (1.f / ((float)cnt + EPSF)) * inv_nobj;             // qw_att
}

// ---------------- Kernel 3: N x K pairwise attraction/repulsion ----------------
// grid: (ceil(n / (256*HP)), KOBJ/KC). Each thread: HP hits x KC objects.
__global__ __launch_bounds__(256)
void k_pair(const float* __restrict__ beta_in, const float* __restrict__ cc,
            const int* __restrict__ tidx, Ws* ws, int n, int xspan)
{
    __shared__ float4 sk[KC];
    int kbase = blockIdx.y * KC;
    if (threadIdx.x < KC)
        sk[threadIdx.x] = ((const float4*)ws->kvec)[kbase + threadIdx.x];
    __syncthreads();

    int i0 = blockIdx.x * 256 + threadIdx.x;

    float c0[HP], c1[HP], q[HP], acc[HP];
    int   k0[HP];
#pragma unroll
    for (int j = 0; j < HP; ++j) {
        int i = i0 + j * xspan;
        bool v = (i < n);
        // invalid lanes: park far away -> relu(1 - r) == 0, k0 = -1 guards att
        c0[j] = v ? cc[2*i]     : 1e30f;
        c1[j] = v ? cc[2*i + 1] : 1e30f;
        float b = v ? clipb(beta_in[i]) : 0.5f;
        float at = 0.5f * logf((1.f + b) / (1.f - b));
        q[j] = at * at + QMIN;
        k0[j] = v ? tidx[i] : -1;
        acc[j] = 0.f;
    }

#pragma unroll 4
    for (int k = 0; k < KC; ++k) {
        float4 kv = sk[k];
#pragma unroll
        for (int j = 0; j < HP; ++j) {
            float dx = c0[j] - kv.x, dy = c1[j] - kv.y;
            float d2 = dx*dx + dy*dy;
            float r  = sqrtf(d2 + 1e-6f);
            acc[j] = fmaf(fmaxf(1.f - r, 0.f), kv.z, acc[j]);
        }
    }

    float att = 0.f, rep = 0.f;
#pragma unroll
    for (int j = 0; j < HP; ++j) {
        int kk = k0[j] - kbase;
        if (kk >= 0 && kk < KC) {
            // remove self-repulsion with the same fp formula (error ~ulp, << tol)
            float4 kv = sk[kk];
            float dx = c0[j] - kv.x, dy = c1[j] - kv.y;
            float d2 = dx*dx + dy*dy;
            float r  = sqrtf(d2 + 1e-6f);
            acc[j] -= fmaxf(1.f - r, 0.f) * kv.z;
            att = fmaf(d2 * kv.w, q[j], att);
        }
        rep = fmaf(acc[j], q[j], rep);
    }

    __shared__ float s0[4], s1[4];
    float A = waveSum(att), R = waveSum(rep);
    int lane = threadIdx.x & 63, w = threadIdx.x >> 6;
    if (lane == 0) { s0[w] = A; s1[w] = R; }
    __syncthreads();
    if (threadIdx.x == 0) {
        float sa = 0.f, sr = 0.f;
        for (int j = 0; j < 4; ++j) { sa += s0[j]; sr += s1[j]; }
        atomicAdd(&ws->scal[0], sa);
        atomicAdd(&ws->scal[1], sr);
    }
}

// ---------------- Kernel 4: final combine ----------------
__global__ void k_final(Ws* ws, float* out, int n)
{
    float L_noise = ws->scal[2] / (ws->scal[3] + EPSF);
    float L_cc    = 0.001f * ws->scal[4] / (float)(n * 2);
    out[0] = ws->scal[0] + ws->scal[1] + ws->scal[5] + L_noise + L_cc;
}

extern "C" void kernel_launch(void* const* d_in, const int* in_sizes, int n_in,
                              void* d_out, int out_size, void* d_ws, size_t ws_size,
                              hipStream_t stream)
{
    const float* pred_beta    = (const float*)d_in[0];
    const float* pred_ccoords = (const float*)d_in[1];
    const float* pred_energy  = (const float*)d_in[2];
    const float* pred_pos     = (const float*)d_in[3];
    const float* pred_time    = (const float*)d_in[4];
    const float* pred_id      = (const float*)d_in[5];
    const int*   t_idx        = (const int*)d_in[6];
    const float* t_energy     = (const float*)d_in[7];
    const float* t_pos        = (const float*)d_in[8];
    const float* t_time       = (const float*)d_in[9];
    // t_pid (d_in[10]) unused by the reference's classification loss

    float* out = (float*)d_out;
    Ws* ws = (Ws*)d_ws;
    const int n = in_sizes[0];   // 80000

    // only the scalar accumulators need zeroing (32 B); partials + kvec are
    // fully overwritten every call
    hipMemsetAsync(ws->scal, 0, sizeof(ws->scal), stream);

    k_hits<<<NB, 1024, 0, stream>>>(pred_beta, pred_ccoords, pred_energy, pred_pos,
                                    pred_time, pred_id, t_idx, t_energy, t_pos,
                                    t_time, ws, n);
    k_obj<<<1, KOBJ, 0, stream>>>(pred_beta, pred_ccoords, ws, n);

    const int B = 256;
    const int GX = (n + B * HP - 1) / (B * HP);      // 79 for n=80000
    dim3 gp(GX, KOBJ / KC);                          // 79 x 8 = 632 blocks
    k_pair<<<gp, B, 0, stream>>>(pred_beta, pred_ccoords, t_idx, ws, n, GX * B);

    k_final<<<1, 1, 0, stream>>>(ws, out, n);
}